// Round 5
// baseline (292.770 us; speedup 1.0000x reference)
//
#include <hip/hip_runtime.h>
#include <hip/hip_bf16.h>
#include <stdint.h>

// Problem constants (fixed by reference):
#define BB 8192      // batch
#define DD 512       // feature dim
#define NNEG 8       // NUM_NEG_CANDIDATES
#define CAP 256      // per-wave survivor buffer (E[survivors] ~ 41)
// TEMPERATURE = 0.5 -> multiply logits by 2.0

// Threshold in the full 32-bit bits domain: (8388608-41984)<<9.
// P(pass) = 41984/2^23 ~= 0.50%, E[count over 8192] ~= 41.
// P(fewer than 8 *diff-label* survivors) ~ Poisson(40) tail ~ 1e-11/row;
// exact widening-window fallback below regardless.
#define VTHI 4273471488u

__host__ __device__ __forceinline__ uint32_t rotl32(uint32_t x, int r) {
#if defined(__HIP_DEVICE_COMPILE__)
  return __builtin_amdgcn_alignbit(x, x, 32 - r);  // v_alignbit_b32
#else
  return (x << r) | (x >> (32 - r));
#endif
}

#define TF_RND(x0, x1, R) { x0 += x1; x1 = rotl32(x1, R); x1 ^= x0; }

// Full threefry2x32 (exact JAX schedule) — host-side key derivation.
__host__ __device__ __forceinline__ void threefry2x32(uint32_t k0, uint32_t k1,
                                                      uint32_t x0, uint32_t x1,
                                                      uint32_t& o0, uint32_t& o1) {
  uint32_t ks2 = k0 ^ k1 ^ 0x1BD11BDAu;
  x0 += k0; x1 += k1;
  TF_RND(x0, x1, 13) TF_RND(x0, x1, 15) TF_RND(x0, x1, 26) TF_RND(x0, x1, 6)
  x0 += k1; x1 += ks2 + 1u;
  TF_RND(x0, x1, 17) TF_RND(x0, x1, 29) TF_RND(x0, x1, 16) TF_RND(x0, x1, 24)
  x0 += ks2; x1 += k0 + 2u;
  TF_RND(x0, x1, 13) TF_RND(x0, x1, 15) TF_RND(x0, x1, 26) TF_RND(x0, x1, 6)
  x0 += k0; x1 += k1 + 3u;
  TF_RND(x0, x1, 17) TF_RND(x0, x1, 29) TF_RND(x0, x1, 16) TF_RND(x0, x1, 24)
  x0 += k1; x1 += ks2 + 4u;
  TF_RND(x0, x1, 13) TF_RND(x0, x1, 15) TF_RND(x0, x1, 26) TF_RND(x0, x1, 6)
  x0 += ks2; x1 += k0 + 5u;
  o0 = x0; o1 = x1;
}

// Single-chain uniform-key variant (fallback paths / positive pass).
__device__ __forceinline__ void tf_uniform(uint32_t k0, uint32_t k1, uint32_t x1pk,
                                           uint32_t& o0, uint32_t& o1) {
  uint32_t ks2 = k0 ^ k1 ^ 0x1BD11BDAu;
  uint32_t x0 = k0, x1 = x1pk;
  TF_RND(x0, x1, 13) TF_RND(x0, x1, 15) TF_RND(x0, x1, 26) TF_RND(x0, x1, 6)
  x0 += k1; x1 += ks2 + 1u;
  TF_RND(x0, x1, 17) TF_RND(x0, x1, 29) TF_RND(x0, x1, 16) TF_RND(x0, x1, 24)
  x0 += ks2; x1 += k0 + 2u;
  TF_RND(x0, x1, 13) TF_RND(x0, x1, 15) TF_RND(x0, x1, 26) TF_RND(x0, x1, 6)
  x0 += k0; x1 += k1 + 3u;
  TF_RND(x0, x1, 17) TF_RND(x0, x1, 29) TF_RND(x0, x1, 16) TF_RND(x0, x1, 24)
  x0 += k1; x1 += ks2 + 4u;
  TF_RND(x0, x1, 13) TF_RND(x0, x1, 15) TF_RND(x0, x1, 26) TF_RND(x0, x1, 6)
  x0 += ks2; x1 += k0 + 5u;
  o0 = x0; o1 = x1;
}

// 4-wide interleaved uniform-key threefry: 4 independent chains in ONE basic
// block -> in-wave ILP=4 hides the ~4-cyc dependent-op latency.
#define RND4(R) { TF_RND(x0a, x1a, R) TF_RND(x0b, x1b, R) TF_RND(x0c, x1c, R) TF_RND(x0d, x1d, R) }
#define INJ4(A, B) { uint32_t _b = (B); \
  x0a += (A); x1a += _b; x0b += (A); x1b += _b; x0c += (A); x1c += _b; x0d += (A); x1d += _b; }

__device__ __forceinline__ void tf_uniform4(uint32_t k0, uint32_t k1, uint32_t ctr,
                                            uint32_t bits[4]) {
  uint32_t ks2 = k0 ^ k1 ^ 0x1BD11BDAu;
  uint32_t x0a = k0, x1a = ctr;
  uint32_t x0b = k0, x1b = ctr + 64u;
  uint32_t x0c = k0, x1c = ctr + 128u;
  uint32_t x0d = k0, x1d = ctr + 192u;
  RND4(13) RND4(15) RND4(26) RND4(6)
  INJ4(k1, ks2 + 1u)
  RND4(17) RND4(29) RND4(16) RND4(24)
  INJ4(ks2, k0 + 2u)
  RND4(13) RND4(15) RND4(26) RND4(6)
  INJ4(k0, k1 + 3u)
  RND4(17) RND4(29) RND4(16) RND4(24)
  INJ4(k1, ks2 + 4u)
  RND4(13) RND4(15) RND4(26) RND4(6)
  INJ4(ks2, k0 + 5u)
  bits[0] = x0a ^ x1a; bits[1] = x0b ^ x1b; bits[2] = x0c ^ x1c; bits[3] = x0d ^ x1d;
}

__device__ __forceinline__ unsigned long long u64max(unsigned long long a, unsigned long long b) {
  return a > b ? a : b;
}
#define CE_DESC(m, x, y) { if (m[x] < m[y]) { unsigned long long _t = m[x]; m[x] = m[y]; m[y] = _t; } }
#define TOP8_INSERT(top, key) \
  if ((key) > top[7]) { \
    top[7] = (key); \
    _Pragma("unroll") \
    for (int s = 7; s > 0; --s) { \
      if (top[s] > top[s - 1]) { \
        unsigned long long _tt = top[s - 1]; top[s - 1] = top[s]; top[s] = _tt; \
      } \
    } \
  }

__device__ __forceinline__ void wave_merge_top8(unsigned long long top[8]) {
  #pragma unroll
  for (int d = 1; d < 64; d <<= 1) {
    unsigned long long o[8];
    #pragma unroll
    for (int r = 0; r < 8; ++r) o[r] = __shfl_xor(top[r], d, 64);
    unsigned long long m[8];
    #pragma unroll
    for (int r = 0; r < 8; ++r) m[r] = u64max(top[r], o[7 - r]);
    CE_DESC(m, 0, 4) CE_DESC(m, 1, 5) CE_DESC(m, 2, 6) CE_DESC(m, 3, 7)
    CE_DESC(m, 0, 2) CE_DESC(m, 1, 3) CE_DESC(m, 4, 6) CE_DESC(m, 5, 7)
    CE_DESC(m, 0, 1) CE_DESC(m, 2, 3) CE_DESC(m, 4, 5) CE_DESC(m, 6, 7)
    #pragma unroll
    for (int r = 0; r < 8; ++r) top[r] = m[r];
  }
}

// ---------------- kernel 1: label lists (block 0) + inverse row norms ----------------
__global__ __launch_bounds__(256) void prep_kernel(const float* __restrict__ feat,
                                                   const int* __restrict__ labels,
                                                   float* __restrict__ inv_norm,
                                                   uint16_t* __restrict__ lists,
                                                   int* __restrict__ offs) {
  if (blockIdx.x == 0) {
    __shared__ uint32_t hist[64];
    __shared__ uint32_t base[64];
    int t = threadIdx.x;
    if (t < 64) hist[t] = 0u;
    __syncthreads();
    for (int e = t; e < BB; e += 256) atomicAdd(&hist[labels[e] & 63], 1u);
    __syncthreads();
    if (t == 0) {
      uint32_t s = 0;
      for (int l = 0; l < 64; ++l) { base[l] = s; offs[l] = (int)s; s += hist[l]; }
      offs[64] = (int)s;
    }
    __syncthreads();
    for (int e = t; e < BB; e += 256) {
      uint32_t p = atomicAdd(&base[labels[e] & 63], 1u);
      lists[p] = (uint16_t)e;   // order within a label is irrelevant (exact argmax key)
    }
  } else {
    int wave = threadIdx.x >> 6, lane = threadIdx.x & 63;
    int row = (blockIdx.x - 1) * 4 + wave;
    const float4* fr = (const float4*)(feat + (size_t)row * DD);
    float4 a = fr[lane], b = fr[lane + 64];
    float s = a.x * a.x + a.y * a.y + a.z * a.z + a.w * a.w
            + b.x * b.x + b.y * b.y + b.z * b.z + b.w * b.w;
    #pragma unroll
    for (int d = 1; d < 64; d <<= 1) s += __shfl_xor(s, d, 64);
    if (lane == 0) inv_norm[row] = 1.0f / fmaxf(sqrtf(s), 1e-12f);
  }
}

// ---------------- kernel 2: selection (scan + positive + top-8) ----------------
__global__ __launch_bounds__(256) void scan_kernel(const int* __restrict__ labels,
                                                   const uint16_t* __restrict__ lists,
                                                   const int* __restrict__ offs,
                                                   uint32_t kp0, uint32_t kp1,
                                                   uint32_t kn0, uint32_t kn1,
                                                   int* __restrict__ pos_j,
                                                   int* __restrict__ neg_idx) {
  __shared__ uint2 buf[4][CAP];     // per-wave survivor buffers (8 KB)
  int wave = threadIdx.x >> 6, lane = threadIdx.x & 63;
  int i = blockIdx.x * 4 + wave;
  int li = labels[i];
  uint32_t rowbase = (uint32_t)i * (uint32_t)BB;
  uint32_t count = 0;               // wave-uniform (SGPR)

  // ---- hot loop: 4 straight-line threefry chains, then ballot-appends ----
  uint32_t cb = rowbase + kn1 + (uint32_t)lane;
  for (int it = 0; it < BB / 256; ++it) {
    uint32_t bits[4];
    tf_uniform4(kn0, kn1, cb + (uint32_t)(it * 256), bits);
    #pragma unroll
    for (int c = 0; c < 4; ++c) {
      bool cand = bits[c] >= VTHI;                 // ~0.5% of lanes
      unsigned long long m = __ballot(cand);
      if (m) {
        if (cand) {
          int ofs = __builtin_amdgcn_mbcnt_hi((uint32_t)(m >> 32),
                     __builtin_amdgcn_mbcnt_lo((uint32_t)m, 0));
          uint32_t p = count + (uint32_t)ofs;
          if (p < CAP) {
            uint2 e; e.x = bits[c]; e.y = (uint32_t)(it * 256 + c * 64 + lane);
            buf[wave][p] = e;
          }
        }
        count += (uint32_t)__popcll(m);
      }
    }
  }

  // ---- positive: EXACT argmax over own-label list (~128 entries, uniform kp) ----
  unsigned long long best = 0ull;
  int beg = offs[li], end = offs[li + 1];
  for (int t = beg + lane; t < end; t += 64) {
    int j = lists[t];
    if (j != i) {
      uint32_t o0, o1;
      tf_uniform(kp0, kp1, rowbase + kp1 + (uint32_t)j, o0, o1);
      unsigned long long key =
          (((unsigned long long)((o0 ^ o1) >> 9) << 13) | (unsigned)(8191 - j)) + 1ull;
      best = u64max(best, key);
    }
  }
  #pragma unroll
  for (int d = 1; d < 64; d <<= 1) best = u64max(best, __shfl_xor(best, d, 64));

  // ---- post-pass: exact top-8 negatives from ~41 survivors (label-filtered) ----
  unsigned long long top[8] = {0ull,0ull,0ull,0ull,0ull,0ull,0ull,0ull};
  if (count <= CAP) {
    for (int t = lane; t < (int)count; t += 64) {
      uint2 e = buf[wave][t];
      uint32_t j = e.y;
      if (labels[j] != li) {
        unsigned long long key =
            (((unsigned long long)(e.x >> 9) << 13) | (unsigned)(8191u - j)) + 1ull;
        TOP8_INSERT(top, key)
      }
    }
  } else {
    // unreachable safety (buffer overflow): exact full rescan
    for (int j = lane; j < BB; j += 64) {
      if (labels[j] != li) {
        uint32_t o0, o1;
        tf_uniform(kn0, kn1, rowbase + kn1 + (uint32_t)j, o0, o1);
        unsigned long long key =
            (((unsigned long long)((o0 ^ o1) >> 9) << 13) | (unsigned)(8191 - j)) + 1ull;
        TOP8_INSERT(top, key)
      }
    }
  }
  wave_merge_top8(top);

  // ---- exact widening-window fallback: fewer than 8 above VTHI (P ~ 1e-11/row) ----
  uint32_t hi = VTHI;
  while (top[7] == 0ull && hi != 0u) {   // wave-uniform after merge
    unsigned long long W = 0x100000000ull - (unsigned long long)hi;
    uint32_t newhi = (W * 8ull >= 0x100000000ull) ? 0u
                     : (uint32_t)(0x100000000ull - W * 8ull);
    for (int j = lane; j < BB; j += 64) {
      if (labels[j] != li) {
        uint32_t o0, o1;
        tf_uniform(kn0, kn1, rowbase + kn1 + (uint32_t)j, o0, o1);
        uint32_t bits = o0 ^ o1;
        if (bits >= newhi && bits < hi) {
          unsigned long long key =
              (((unsigned long long)(bits >> 9) << 13) | (unsigned)(8191 - j)) + 1ull;
          TOP8_INSERT(top, key)
        }
      }
    }
    wave_merge_top8(top);
    hi = newhi;
  }

  if (lane == 0) {
    pos_j[i] = best ? (8191 - (int)((best - 1ull) & 0x1FFFull)) : 0;
    #pragma unroll
    for (int r = 0; r < NNEG; ++r)
      neg_idx[i * 8 + r] = top[r] ? (8191 - (int)((top[r] - 1ull) & 0x1FFFull)) : r;
  }
}

// ---------------- kernel 3: 9 dots + logsumexp + mean ----------------
__global__ __launch_bounds__(256) void loss_kernel(const float* __restrict__ feat,
                                                   const float* __restrict__ inv_norm,
                                                   const int* __restrict__ pos_j,
                                                   const int* __restrict__ neg_idx,
                                                   float* __restrict__ out) {
  __shared__ float part[4];
  int wave = threadIdx.x >> 6, lane = threadIdx.x & 63;
  int i = blockIdx.x * 4 + wave;
  const float4* fi = (const float4*)(feat + (size_t)i * DD);
  float4 a0 = fi[lane], a1 = fi[lane + 64];

  int cand[9];
  cand[0] = pos_j[i];
  #pragma unroll
  for (int m = 0; m < NNEG; ++m) cand[m + 1] = neg_idx[i * 8 + m];

  // issue all 18 16B loads first (MLP), then FMA
  float4 c0[9], c1[9];
  #pragma unroll
  for (int c = 0; c < 9; ++c) {
    const float4* fc = (const float4*)(feat + (size_t)cand[c] * DD);
    c0[c] = fc[lane];
    c1[c] = fc[lane + 64];
  }
  float dots[9];
  #pragma unroll
  for (int c = 0; c < 9; ++c) {
    float s;
    s = a0.x * c0[c].x;
    s = fmaf(a0.y, c0[c].y, s); s = fmaf(a0.z, c0[c].z, s); s = fmaf(a0.w, c0[c].w, s);
    s = fmaf(a1.x, c1[c].x, s); s = fmaf(a1.y, c1[c].y, s);
    s = fmaf(a1.z, c1[c].z, s); s = fmaf(a1.w, c1[c].w, s);
    dots[c] = s;
  }
  #pragma unroll
  for (int c = 0; c < 9; ++c) {
    #pragma unroll
    for (int d = 1; d < 64; d <<= 1) dots[c] += __shfl_xor(dots[c], d, 64);
  }

  if (lane == 0) {
    float inv_i = inv_norm[i];
    float pos = dots[0] * inv_i * inv_norm[cand[0]] * 2.0f;  // /TEMPERATURE
    float t1 = -1e30f, t2 = -1e30f, t3 = -1e30f;             // top-3 of 8 negatives
    #pragma unroll
    for (int m = 0; m < NNEG; ++m) {
      float v = dots[m + 1] * inv_i * inv_norm[cand[m + 1]] * 2.0f;
      if (v > t1)      { t3 = t2; t2 = t1; t1 = v; }
      else if (v > t2) { t3 = t2; t2 = v; }
      else if (v > t3) { t3 = v; }
    }
    float mx = fmaxf(fmaxf(pos, t1), fmaxf(t2, t3));
    float lse = mx + logf(__expf(pos - mx) + __expf(t1 - mx) + __expf(t2 - mx) + __expf(t3 - mx));
    part[wave] = (lse - pos) * (1.0f / (float)BB);
  }
  __syncthreads();
  if (threadIdx.x == 0) atomicAdd(out, part[0] + part[1] + part[2] + part[3]);
}

// ---------------- launch ----------------
extern "C" void kernel_launch(void* const* d_in, const int* in_sizes, int n_in,
                              void* d_out, int out_size, void* d_ws, size_t ws_size,
                              hipStream_t stream) {
  const float* features = (const float*)d_in[0];
  const int* labels = (const int*)d_in[1];
  float* out = (float*)d_out;

  // workspace: inv_norm f32[8192] | lists u16[8192] | offs i32[65](+pad) | pos_j i32[8192] | neg_idx i32[8192*8]
  char* w = (char*)d_ws;
  float* inv_norm = (float*)w;                    w += BB * sizeof(float);
  uint16_t* lists = (uint16_t*)w;                 w += BB * sizeof(uint16_t);
  int* offs = (int*)w;                            w += 65 * sizeof(int) + 28;  // pad to 16B
  int* pos_j = (int*)w;                           w += BB * sizeof(int);
  int* neg_idx = (int*)w;

  // JAX partitionable split of key(42) = (0,42)
  uint32_t kp0, kp1, kn0, kn1;
  threefry2x32(0u, 42u, 0u, 0u, kp0, kp1);
  threefry2x32(0u, 42u, 0u, 1u, kn0, kn1);

  hipMemsetAsync(d_out, 0, sizeof(float), stream);
  prep_kernel<<<BB / 4 + 1, 256, 0, stream>>>(features, labels, inv_norm, lists, offs);
  scan_kernel<<<BB / 4, 256, 0, stream>>>(labels, lists, offs, kp0, kp1, kn0, kn1,
                                          pos_j, neg_idx);
  loss_kernel<<<BB / 4, 256, 0, stream>>>(features, inv_norm, pos_j, neg_idx, out);
}

// Round 6
// 250.960 us; speedup vs baseline: 1.1666x; 1.1666x over previous
//
#include <hip/hip_runtime.h>
#include <stdint.h>

// Problem constants (fixed by reference):
#define BB 8192      // batch
#define DD 512       // feature dim
#define NNEG 8       // NUM_NEG_CANDIDATES
#define CAP 256      // per-wave survivor buffer (E[survivors] ~ 41)
#define LSTRIDE 512  // per-label list segment (mean 128, +11 sigma < 512)
// TEMPERATURE = 0.5 -> multiply logits by 2.0

// Threshold in the full 32-bit bits domain: (8388608-41984)<<9.
// P(pass) = 41984/2^23 ~= 0.50%, E[count over 8192] ~= 41.
// P(fewer than 8 *diff-label* survivors) ~ Poisson(40) tail ~ 1e-11/row;
// exact widening-window fallback below regardless.
#define VTHI 4273471488u

__host__ __device__ __forceinline__ uint32_t rotl32(uint32_t x, int r) {
#if defined(__HIP_DEVICE_COMPILE__)
  return __builtin_amdgcn_alignbit(x, x, 32 - r);  // v_alignbit_b32
#else
  return (x << r) | (x >> (32 - r));
#endif
}

#define TF_RND(x0, x1, R) { x0 += x1; x1 = rotl32(x1, R); x1 ^= x0; }

// Full threefry2x32 (exact JAX schedule) — host-side key derivation.
__host__ __device__ __forceinline__ void threefry2x32(uint32_t k0, uint32_t k1,
                                                      uint32_t x0, uint32_t x1,
                                                      uint32_t& o0, uint32_t& o1) {
  uint32_t ks2 = k0 ^ k1 ^ 0x1BD11BDAu;
  x0 += k0; x1 += k1;
  TF_RND(x0, x1, 13) TF_RND(x0, x1, 15) TF_RND(x0, x1, 26) TF_RND(x0, x1, 6)
  x0 += k1; x1 += ks2 + 1u;
  TF_RND(x0, x1, 17) TF_RND(x0, x1, 29) TF_RND(x0, x1, 16) TF_RND(x0, x1, 24)
  x0 += ks2; x1 += k0 + 2u;
  TF_RND(x0, x1, 13) TF_RND(x0, x1, 15) TF_RND(x0, x1, 26) TF_RND(x0, x1, 6)
  x0 += k0; x1 += k1 + 3u;
  TF_RND(x0, x1, 17) TF_RND(x0, x1, 29) TF_RND(x0, x1, 16) TF_RND(x0, x1, 24)
  x0 += k1; x1 += ks2 + 4u;
  TF_RND(x0, x1, 13) TF_RND(x0, x1, 15) TF_RND(x0, x1, 26) TF_RND(x0, x1, 6)
  x0 += ks2; x1 += k0 + 5u;
  o0 = x0; o1 = x1;
}

// Single-chain uniform-key variant (positive pass / fallback paths).
__device__ __forceinline__ void tf_uniform(uint32_t k0, uint32_t k1, uint32_t x1pk,
                                           uint32_t& o0, uint32_t& o1) {
  uint32_t ks2 = k0 ^ k1 ^ 0x1BD11BDAu;
  uint32_t x0 = k0, x1 = x1pk;
  TF_RND(x0, x1, 13) TF_RND(x0, x1, 15) TF_RND(x0, x1, 26) TF_RND(x0, x1, 6)
  x0 += k1; x1 += ks2 + 1u;
  TF_RND(x0, x1, 17) TF_RND(x0, x1, 29) TF_RND(x0, x1, 16) TF_RND(x0, x1, 24)
  x0 += ks2; x1 += k0 + 2u;
  TF_RND(x0, x1, 13) TF_RND(x0, x1, 15) TF_RND(x0, x1, 26) TF_RND(x0, x1, 6)
  x0 += k0; x1 += k1 + 3u;
  TF_RND(x0, x1, 17) TF_RND(x0, x1, 29) TF_RND(x0, x1, 16) TF_RND(x0, x1, 24)
  x0 += k1; x1 += ks2 + 4u;
  TF_RND(x0, x1, 13) TF_RND(x0, x1, 15) TF_RND(x0, x1, 26) TF_RND(x0, x1, 6)
  x0 += ks2; x1 += k0 + 5u;
  o0 = x0; o1 = x1;
}

// 4-wide interleaved uniform-key threefry with v_add3 injection folding:
// the x0 group-boundary injection is folded into the next round's x0 += x1
// as x0 = x0 + A + x1 (one v_add3_u32). ~66 VALU/element.
#define RND4(R) { TF_RND(x0a, x1a, R) TF_RND(x0b, x1b, R) TF_RND(x0c, x1c, R) TF_RND(x0d, x1d, R) }
#define RND4_F(R, A) { \
  x0a = x0a + (A) + x1a; x1a = rotl32(x1a, R); x1a ^= x0a; \
  x0b = x0b + (A) + x1b; x1b = rotl32(x1b, R); x1b ^= x0b; \
  x0c = x0c + (A) + x1c; x1c = rotl32(x1c, R); x1c ^= x0c; \
  x0d = x0d + (A) + x1d; x1d = rotl32(x1d, R); x1d ^= x0d; }
#define INJX1_4(B) { uint32_t _b = (B); x1a += _b; x1b += _b; x1c += _b; x1d += _b; }

__device__ __forceinline__ void tf_uniform4(uint32_t k0, uint32_t k1, uint32_t ctr,
                                            uint32_t bits[4]) {
  uint32_t ks2 = k0 ^ k1 ^ 0x1BD11BDAu;
  uint32_t x0a = k0, x1a = ctr;
  uint32_t x0b = k0, x1b = ctr + 64u;
  uint32_t x0c = k0, x1c = ctr + 128u;
  uint32_t x0d = k0, x1d = ctr + 192u;
  RND4(13) RND4(15) RND4(26) RND4(6)
  INJX1_4(ks2 + 1u)
  RND4_F(17, k1) RND4(29) RND4(16) RND4(24)
  INJX1_4(k0 + 2u)
  RND4_F(13, ks2) RND4(15) RND4(26) RND4(6)
  INJX1_4(k1 + 3u)
  RND4_F(17, k0) RND4(29) RND4(16) RND4(24)
  INJX1_4(ks2 + 4u)
  RND4_F(13, k1) RND4(15) RND4(26) RND4(6)
  uint32_t c5 = k0 + 5u;
  bits[0] = (x0a + ks2) ^ (x1a + c5);
  bits[1] = (x0b + ks2) ^ (x1b + c5);
  bits[2] = (x0c + ks2) ^ (x1c + c5);
  bits[3] = (x0d + ks2) ^ (x1d + c5);
}

__device__ __forceinline__ unsigned long long u64max(unsigned long long a, unsigned long long b) {
  return a > b ? a : b;
}
#define CE_DESC(m, x, y) { if (m[x] < m[y]) { unsigned long long _t = m[x]; m[x] = m[y]; m[y] = _t; } }
#define TOP8_INSERT(top, key) \
  if ((key) > top[7]) { \
    top[7] = (key); \
    _Pragma("unroll") \
    for (int s = 7; s > 0; --s) { \
      if (top[s] > top[s - 1]) { \
        unsigned long long _tt = top[s - 1]; top[s - 1] = top[s]; top[s] = _tt; \
      } \
    } \
  }

__device__ __forceinline__ void wave_merge_top8(unsigned long long top[8]) {
  #pragma unroll
  for (int d = 1; d < 64; d <<= 1) {
    unsigned long long o[8];
    #pragma unroll
    for (int r = 0; r < 8; ++r) o[r] = __shfl_xor(top[r], d, 64);
    unsigned long long m[8];
    #pragma unroll
    for (int r = 0; r < 8; ++r) m[r] = u64max(top[r], o[7 - r]);
    CE_DESC(m, 0, 4) CE_DESC(m, 1, 5) CE_DESC(m, 2, 6) CE_DESC(m, 3, 7)
    CE_DESC(m, 0, 2) CE_DESC(m, 1, 3) CE_DESC(m, 4, 6) CE_DESC(m, 5, 7)
    CE_DESC(m, 0, 1) CE_DESC(m, 2, 3) CE_DESC(m, 4, 5) CE_DESC(m, 6, 7)
    #pragma unroll
    for (int r = 0; r < 8; ++r) top[r] = m[r];
  }
}

// ---------------- kernel 1: per-label index lists (64 blocks, no scan) ----------------
__global__ __launch_bounds__(256) void prep_kernel(const int* __restrict__ labels,
                                                   uint16_t* __restrict__ lists,
                                                   int* __restrict__ cnts) {
  __shared__ uint32_t c;
  int l = blockIdx.x;
  if (threadIdx.x == 0) c = 0u;
  __syncthreads();
  for (int t = threadIdx.x; t < BB; t += 256) {
    if (labels[t] == l) {
      uint32_t p = atomicAdd(&c, 1u);
      if (p < LSTRIDE) lists[l * LSTRIDE + p] = (uint16_t)t;  // order irrelevant (exact key)
    }
  }
  __syncthreads();
  if (threadIdx.x == 0) cnts[l] = (int)c;
}

// ---------------- kernel 2: scan + selection + fused loss ----------------
__global__ __launch_bounds__(256) void main_kernel(const float* __restrict__ feat,
                                                   const int* __restrict__ labels,
                                                   const uint16_t* __restrict__ lists,
                                                   const int* __restrict__ cnts,
                                                   uint32_t kp0, uint32_t kp1,
                                                   uint32_t kn0, uint32_t kn1,
                                                   float* __restrict__ out) {
  __shared__ uint2 buf[4][CAP];     // per-wave survivor buffers (8 KB)
  __shared__ float part[4];
  int wave = threadIdx.x >> 6, lane = threadIdx.x & 63;
  int i = blockIdx.x * 4 + wave;
  int li = labels[i];
  uint32_t rowbase = (uint32_t)i * (uint32_t)BB;
  uint32_t count = 0;               // wave-uniform (SGPR)

  // ---- hot loop: 4 straight-line threefry chains, then ballot-appends ----
  uint32_t cb = rowbase + kn1 + (uint32_t)lane;
  for (int it = 0; it < BB / 256; ++it) {
    uint32_t bits[4];
    tf_uniform4(kn0, kn1, cb + (uint32_t)(it * 256), bits);
    #pragma unroll
    for (int c = 0; c < 4; ++c) {
      bool cand = bits[c] >= VTHI;                 // ~0.5% of lanes
      unsigned long long m = __ballot(cand);
      if (m) {
        if (cand) {
          int ofs = __builtin_amdgcn_mbcnt_hi((uint32_t)(m >> 32),
                     __builtin_amdgcn_mbcnt_lo((uint32_t)m, 0));
          uint32_t p = count + (uint32_t)ofs;
          if (p < CAP) {
            uint2 e; e.x = bits[c]; e.y = (uint32_t)(it * 256 + c * 64 + lane);
            buf[wave][p] = e;
          }
        }
        count += (uint32_t)__popcll(m);
      }
    }
  }

  // ---- positive: EXACT argmax over own-label list (~128 entries, uniform kp) ----
  unsigned long long best = 0ull;
  int lc = cnts[li];
  if (lc <= LSTRIDE) {
    const uint16_t* seg = lists + li * LSTRIDE;
    for (int t = lane; t < lc; t += 64) {
      int j = seg[t];
      if (j != i) {
        uint32_t o0, o1;
        tf_uniform(kp0, kp1, rowbase + kp1 + (uint32_t)j, o0, o1);
        unsigned long long key =
            (((unsigned long long)((o0 ^ o1) >> 9) << 13) | (unsigned)(8191 - j)) + 1ull;
        best = u64max(best, key);
      }
    }
  } else {
    // unreachable safety (label multiplicity > LSTRIDE): exact full label scan
    for (int j = lane; j < BB; j += 64) {
      if (labels[j] == li && j != i) {
        uint32_t o0, o1;
        tf_uniform(kp0, kp1, rowbase + kp1 + (uint32_t)j, o0, o1);
        unsigned long long key =
            (((unsigned long long)((o0 ^ o1) >> 9) << 13) | (unsigned)(8191 - j)) + 1ull;
        best = u64max(best, key);
      }
    }
  }
  #pragma unroll
  for (int d = 1; d < 64; d <<= 1) best = u64max(best, __shfl_xor(best, d, 64));

  // ---- post-pass: exact top-8 negatives from ~41 survivors (label-filtered) ----
  unsigned long long top[8] = {0ull,0ull,0ull,0ull,0ull,0ull,0ull,0ull};
  if (count <= CAP) {
    for (int t = lane; t < (int)count; t += 64) {
      uint2 e = buf[wave][t];
      uint32_t j = e.y;
      if (labels[j] != li) {
        unsigned long long key =
            (((unsigned long long)(e.x >> 9) << 13) | (unsigned)(8191u - j)) + 1ull;
        TOP8_INSERT(top, key)
      }
    }
  } else {
    // unreachable safety (buffer overflow): exact full rescan
    for (int j = lane; j < BB; j += 64) {
      if (labels[j] != li) {
        uint32_t o0, o1;
        tf_uniform(kn0, kn1, rowbase + kn1 + (uint32_t)j, o0, o1);
        unsigned long long key =
            (((unsigned long long)((o0 ^ o1) >> 9) << 13) | (unsigned)(8191 - j)) + 1ull;
        TOP8_INSERT(top, key)
      }
    }
  }
  wave_merge_top8(top);

  // ---- exact widening-window fallback: fewer than 8 above VTHI (P ~ 1e-11/row) ----
  uint32_t hi = VTHI;
  while (top[7] == 0ull && hi != 0u) {   // wave-uniform after merge
    unsigned long long W = 0x100000000ull - (unsigned long long)hi;
    uint32_t newhi = (W * 8ull >= 0x100000000ull) ? 0u
                     : (uint32_t)(0x100000000ull - W * 8ull);
    for (int j = lane; j < BB; j += 64) {
      if (labels[j] != li) {
        uint32_t o0, o1;
        tf_uniform(kn0, kn1, rowbase + kn1 + (uint32_t)j, o0, o1);
        uint32_t bits = o0 ^ o1;
        if (bits >= newhi && bits < hi) {
          unsigned long long key =
              (((unsigned long long)(bits >> 9) << 13) | (unsigned)(8191 - j)) + 1ull;
          TOP8_INSERT(top, key)
        }
      }
    }
    wave_merge_top8(top);
    hi = newhi;
  }

  // ---- decode candidates (all lanes hold identical best/top) ----
  int cand[9];
  cand[0] = best ? (8191 - (int)((best - 1ull) & 0x1FFFull)) : 0;
  #pragma unroll
  for (int r = 0; r < NNEG; ++r)
    cand[r + 1] = top[r] ? (8191 - (int)((top[r] - 1ull) & 0x1FFFull)) : r;

  // ---- fused loss epilogue: norms from self-dots, 9 cross-dots, logsumexp ----
  const float4* fi = (const float4*)(feat + (size_t)i * DD);
  float4 a0 = fi[lane], a1 = fi[lane + 64];
  float sii = a0.x * a0.x + a0.y * a0.y + a0.z * a0.z + a0.w * a0.w
            + a1.x * a1.x + a1.y * a1.y + a1.z * a1.z + a1.w * a1.w;
  float dots[9], selfs[9];
  #pragma unroll
  for (int c = 0; c < 9; ++c) {
    const float4* fc = (const float4*)(feat + (size_t)cand[c] * DD);
    float4 c0 = fc[lane], c1 = fc[lane + 64];
    float s;
    s = a0.x * c0.x;
    s = fmaf(a0.y, c0.y, s); s = fmaf(a0.z, c0.z, s); s = fmaf(a0.w, c0.w, s);
    s = fmaf(a1.x, c1.x, s); s = fmaf(a1.y, c1.y, s);
    s = fmaf(a1.z, c1.z, s); s = fmaf(a1.w, c1.w, s);
    dots[c] = s;
    float q;
    q = c0.x * c0.x;
    q = fmaf(c0.y, c0.y, q); q = fmaf(c0.z, c0.z, q); q = fmaf(c0.w, c0.w, q);
    q = fmaf(c1.x, c1.x, q); q = fmaf(c1.y, c1.y, q);
    q = fmaf(c1.z, c1.z, q); q = fmaf(c1.w, c1.w, q);
    selfs[c] = q;
  }
  #pragma unroll
  for (int d = 1; d < 64; d <<= 1) {
    sii += __shfl_xor(sii, d, 64);
    #pragma unroll
    for (int c = 0; c < 9; ++c) {
      dots[c] += __shfl_xor(dots[c], d, 64);
      selfs[c] += __shfl_xor(selfs[c], d, 64);
    }
  }

  if (lane == 0) {
    float inv_i = 1.0f / fmaxf(sqrtf(sii), 1e-12f);
    float inv_c[9];
    #pragma unroll
    for (int c = 0; c < 9; ++c) inv_c[c] = 1.0f / fmaxf(sqrtf(selfs[c]), 1e-12f);
    float pos = dots[0] * inv_i * inv_c[0] * 2.0f;           // /TEMPERATURE
    float t1 = -1e30f, t2 = -1e30f, t3 = -1e30f;             // top-3 of 8 negatives
    #pragma unroll
    for (int m = 0; m < NNEG; ++m) {
      float v = dots[m + 1] * inv_i * inv_c[m + 1] * 2.0f;
      if (v > t1)      { t3 = t2; t2 = t1; t1 = v; }
      else if (v > t2) { t3 = t2; t2 = v; }
      else if (v > t3) { t3 = v; }
    }
    float mx = fmaxf(fmaxf(pos, t1), fmaxf(t2, t3));
    float lse = mx + logf(__expf(pos - mx) + __expf(t1 - mx) + __expf(t2 - mx) + __expf(t3 - mx));
    part[wave] = (lse - pos) * (1.0f / (float)BB);
  }
  __syncthreads();
  if (threadIdx.x == 0) atomicAdd(out, part[0] + part[1] + part[2] + part[3]);
}

// ---------------- launch ----------------
extern "C" void kernel_launch(void* const* d_in, const int* in_sizes, int n_in,
                              void* d_out, int out_size, void* d_ws, size_t ws_size,
                              hipStream_t stream) {
  const float* features = (const float*)d_in[0];
  const int* labels = (const int*)d_in[1];
  float* out = (float*)d_out;

  // workspace: lists u16[64*512] (64 KB) | cnts i32[64]
  uint16_t* lists = (uint16_t*)d_ws;
  int* cnts = (int*)((char*)d_ws + 64 * LSTRIDE * sizeof(uint16_t));

  // JAX partitionable split of key(42) = (0,42)
  uint32_t kp0, kp1, kn0, kn1;
  threefry2x32(0u, 42u, 0u, 0u, kp0, kp1);
  threefry2x32(0u, 42u, 0u, 1u, kn0, kn1);

  hipMemsetAsync(d_out, 0, sizeof(float), stream);
  prep_kernel<<<64, 256, 0, stream>>>(labels, lists, cnts);
  main_kernel<<<BB / 4, 256, 0, stream>>>(features, labels, lists, cnts,
                                          kp0, kp1, kn0, kn1, out);
}